// Round 6
// baseline (215.385 us; speedup 1.0000x reference)
//
#include <hip/hip_runtime.h>
#include <math.h>
#include <stdint.h>

#define B_SZ   8
#define T_SEQ  2048
#define DIM    256
#define NH     32            // B*E
#define DE     64
#define BAND   509           // |j-i|<=509 can have nonzero f32 punish (denormals)
#define M_ROWS (B_SZ * T_SEQ)

typedef __attribute__((ext_vector_type(8))) short short8;   // 8 bf16 (4 VGPRs)
typedef __attribute__((ext_vector_type(4))) float floatx4;  // MFMA C/D frag
typedef unsigned short ushort_t;

__device__ __forceinline__ ushort_t f2bf(float x) {   // RNE f32->bf16
    unsigned u = __float_as_uint(x);
    u += 0x7fffu + ((u >> 16) & 1u);
    return (ushort_t)(u >> 16);
}
__device__ __forceinline__ float bf2f(ushort_t b) {
    return __uint_as_float(((unsigned)b) << 16);
}
__device__ __forceinline__ unsigned pack2(float a, float b) {
    return (unsigned)f2bf(a) | ((unsigned)f2bf(b) << 16);
}

__device__ __forceinline__ double pd_exact(int d, float th) {
    float df  = (float)d;
    float arg = (-(df * df)) / (th * th);      // exact same f32 ops as numpy
    double pdd = exp((double)arg);
    if (pdd < 1.17549435082228751e-38)
        return rint(pdd * 0x1p149) * 0x1p-149; // f32 RNE into denormal range
    return (double)(float)pdd;
}

// ============ prep: x,w -> bf16; pdf[0..383] + thr[|d|-321, 0..287] =========
__global__ __launch_bounds__(256) void prep_kernel(
    const float* __restrict__ x,
    const float* __restrict__ wq, const float* __restrict__ wk,
    const float* __restrict__ wv, const float* __restrict__ wo,
    const float* __restrict__ theta,
    ushort_t* __restrict__ xb, ushort_t* __restrict__ wb,
    float* __restrict__ thr_g, float* __restrict__ pdf_g)
{
    const int bid = blockIdx.x, tid = threadIdx.x;
    if (bid < 2048) {
        size_t i8 = ((size_t)bid * 256 + tid) * 8;
        float4 a = *(const float4*)(x + i8);
        float4 b = *(const float4*)(x + i8 + 4);
        uint4 o;
        o.x = pack2(a.x, a.y); o.y = pack2(a.z, a.w);
        o.z = pack2(b.x, b.y); o.w = pack2(b.z, b.w);
        *(uint4*)(xb + i8) = o;
    } else if (bid < 2176) {
        size_t w8 = ((size_t)(bid - 2048) * 256 + tid) * 8;
        int which = (int)(w8 >> 16);
        const float* src = (which == 0) ? wq : (which == 1) ? wk : (which == 2) ? wv : wo;
        size_t off = w8 & 65535;
        float4 a = *(const float4*)(src + off);
        float4 b = *(const float4*)(src + off + 4);
        uint4 o;
        o.x = pack2(a.x, a.y); o.y = pack2(a.z, a.w);
        o.z = pack2(b.x, b.y); o.w = pack2(b.z, b.w);
        *(uint4*)(wb + w8) = o;
    } else {
        int i = (bid - 2176) * 256 + tid;
        float th = theta[0];
        if (i < 384) pdf_g[i] = (float)pd_exact(i, th);
        if (i < 288) {
            double pdv = pd_exact(321 + i, th);
            // exclusion: RN32(s*pd)==0  <=>  |s| <= 2^-150/pd
            thr_g[i] = (pdv == 0.0) ? __builtin_inff() : (float)(0x1p-150 / pdv);
        }
    }
}

// ============ QKV projection: zero-LDS MFMA GEMM (Q pre-scaled 1/sqrt(T)) ===
// head map: h=b*4+d/64, q=(d%64)*32+t/64, e=t%64.  Qh/Kh masked q>=sl -> 0.
__global__ __launch_bounds__(256, 2) void proj_qkv_mfma(
    const ushort_t* __restrict__ xb, const ushort_t* __restrict__ wb,
    const float* __restrict__ bq, const float* __restrict__ bk,
    const float* __restrict__ bv, const int* __restrict__ seq_len,
    ushort_t* __restrict__ Qh, ushort_t* __restrict__ Kh, ushort_t* __restrict__ Vh)
{
    const int wave = threadIdx.x >> 6, lane = threadIdx.x & 63;
    const int quad = lane >> 4, l15 = lane & 15;
    const int task = blockIdx.x * 4 + wave;      // 3072 tasks
    const int nt64 = task % 12;
    const int mstrip = task / 12;
    const int mode = nt64 >> 2;                  // 0:Q 1:K 2:V
    const int nloc_base = (nt64 & 3) * 64;       // d within [0,256)
    const ushort_t* Wp = wb + (size_t)mode * 65536;
    const int m0 = mstrip * 64;
    const int bb = m0 >> 11;
    const int th0 = (m0 >> 6) & 31;
    const int sl = seq_len[bb];
    ushort_t* outp = (mode == 0) ? Qh : (mode == 1) ? Kh : Vh;
    const float* bias = (mode == 0) ? bq : (mode == 1) ? bk : bv;
    const int hh = bb * 4 + (nloc_base >> 6);
    const float oscale = (mode == 0) ? 0.022097086912079612f : 1.0f;  // 1/sqrt(2048)

    short8 Bf[4][8];
    #pragma unroll
    for (int nt = 0; nt < 4; ++nt) {
        int nrow = nloc_base + nt * 16 + l15;
        #pragma unroll
        for (int ks = 0; ks < 8; ++ks)
            Bf[nt][ks] = *(const short8*)(Wp + (size_t)nrow * 256 + ks * 32 + quad * 8);
    }
    float bias4[4]; int qv[4];
    #pragma unroll
    for (int nt = 0; nt < 4; ++nt) {
        int dl = nloc_base + nt * 16 + l15;
        bias4[nt] = bias[dl];
        qv[nt] = (dl & 63) * 32 + th0;
    }

    short8 Acur[8];
    #pragma unroll
    for (int ks = 0; ks < 8; ++ks)
        Acur[ks] = *(const short8*)(xb + (size_t)(m0 + l15) * 256 + ks * 32 + quad * 8);

    #pragma unroll
    for (int mb = 0; mb < 4; ++mb) {
        const int mb0 = m0 + mb * 16;
        short8 Anext[8];
        if (mb < 3) {
            #pragma unroll
            for (int ks = 0; ks < 8; ++ks)
                Anext[ks] = *(const short8*)(xb + (size_t)(mb0 + 16 + l15) * 256 + ks * 32 + quad * 8);
        }
        floatx4 acc[4];
        #pragma unroll
        for (int nt = 0; nt < 4; ++nt) acc[nt] = (floatx4){0.f, 0.f, 0.f, 0.f};
        #pragma unroll
        for (int ks = 0; ks < 8; ++ks)
            #pragma unroll
            for (int nt = 0; nt < 4; ++nt)
                acc[nt] = __builtin_amdgcn_mfma_f32_16x16x32_bf16(Acur[ks], Bf[nt][ks], acc[nt], 0, 0, 0);
        const int e_base = (mb0 & 63) + quad * 4;
        #pragma unroll
        for (int nt = 0; nt < 4; ++nt) {
            bool msk = (mode <= 1) && (qv[nt] >= sl);
            float v0 = msk ? 0.f : (acc[nt][0] + bias4[nt]) * oscale;
            float v1 = msk ? 0.f : (acc[nt][1] + bias4[nt]) * oscale;
            float v2 = msk ? 0.f : (acc[nt][2] + bias4[nt]) * oscale;
            float v3 = msk ? 0.f : (acc[nt][3] + bias4[nt]) * oscale;
            uint2 pk; pk.x = pack2(v0, v1); pk.y = pack2(v2, v3);
            *(uint2*)(outp + (((size_t)hh * T_SEQ + qv[nt]) << 6) + e_base) = pk;
        }
        #pragma unroll
        for (int ks = 0; ks < 8; ++ks) Acur[ks] = Anext[ks];
    }
}

// ============ V transpose with MFMA-k permutation: VTp[h][e][j'] ============
// phys col c (within each 64-j block) holds j = (c>>2) + 16*(c&3), so that
// attn's Ps b64 writes (col' = l15*4+nt) and V B-frag loads use the same k order
__global__ __launch_bounds__(256) void vtrans_kernel(const ushort_t* __restrict__ Vh,
                                                     ushort_t* __restrict__ VTp)
{
    __shared__ ushort_t Vs[256][66];
    const int tid = threadIdx.x;
    const int h = blockIdx.x >> 3, chunk = blockIdx.x & 7;
    const ushort_t* src = Vh + ((size_t)(h * T_SEQ + chunk * 256)) * DE;
    #pragma unroll
    for (int rep = 0; rep < 8; ++rep) {
        int f = rep * 256 + tid;
        int row = f >> 3, c8 = (f & 7) * 8;
        *(uint4*)&Vs[row][c8] = *(const uint4*)(src + (size_t)row * DE + c8);
    }
    __syncthreads();
    const int w = tid >> 6, lane = tid & 63;
    const int half = lane >> 5;
    const int c32 = lane & 31;
    const int cbase = c32 * 8;
    const int blk = cbase >> 6;
    const int cin = cbase & 63;
    #pragma unroll
    for (int rr = 0; rr < 8; ++rr) {
        int e = w * 16 + rr * 2 + half;
        ushort_t tmp[8];
        #pragma unroll
        for (int t = 0; t < 8; ++t) {
            int ci = cin + t;
            int j = blk * 64 + (ci >> 2) + 16 * (ci & 3);
            tmp[t] = Vs[j][e];
        }
        *(uint4*)(VTp + ((size_t)(h * DE + e)) * T_SEQ + chunk * 256 + cbase) = *(uint4*)tmp;
    }
}

// ============ per-head mean of V (coalesced rows of VTp; perm irrelevant) ===
__global__ __launch_bounds__(256) void meanv_kernel(const ushort_t* __restrict__ VTp,
                                                    float* __restrict__ mv) {
    __shared__ float red[256];
    const int h = blockIdx.x, tid = threadIdx.x;
    const int e = tid >> 2, seg = tid & 3;
    const ushort_t* p = VTp + ((size_t)(h * DE + e)) * T_SEQ + seg * 512;
    float s = 0.f;
    for (int i = 0; i < 512; i += 8) {
        uint4 u = *(const uint4*)(p + i);
        const ushort_t* ww = (const ushort_t*)&u;
        #pragma unroll
        for (int k = 0; k < 8; ++k) s += bf2f(ww[k]);
    }
    red[tid] = s;
    __syncthreads();
    if (seg == 0)
        mv[h * DE + e] = (red[tid] + red[tid+1] + red[tid+2] + red[tid+3]) * (1.0f / T_SEQ);
}

// ============ barrier-free banded flash attention ===========================
// 2048 blocks x 128 thr; block = 32 q-rows of one head; 2 waves split j-band,
// no sync in the loop; one final barrier to combine (c,l) partials.
__global__ __launch_bounds__(128) void attn_mfma_kernel(
    const ushort_t* __restrict__ Qh, const ushort_t* __restrict__ Kh,
    const ushort_t* __restrict__ VTp, const float* __restrict__ thr_g,
    const float* __restrict__ pdf_g, const float* __restrict__ mv,
    const int* __restrict__ seq_len, ushort_t* __restrict__ ctxb)
{
    __shared__ ushort_t Ps[2][32][72];   // per-wave P tile (C->A hop), 144B rows
    __shared__ float cf[32][66];         // wave1 ctx partial (f32)
    __shared__ float lf[32];             // wave1 l partial
    __shared__ float pdfs[384];          // punish, |delta| 0..383
    __shared__ float thrs[288];          // thr, |delta|-321

    const int tid  = threadIdx.x;
    const int wave = tid >> 6;
    const int lane = tid & 63;
    const int quad = lane >> 4;
    const int l15  = lane & 15;
    // XCD swizzle: 4 heads per XCD, all q-strips of a head on one XCD
    const int bid   = blockIdx.x;
    const int inner = bid >> 3;
    const int h  = ((inner >> 6) << 3) | (bid & 7);
    const int q0 = (inner & 63) * 32;
    const int b  = h >> 2;
    const int sl = seq_len[b];
    const float invT = 1.0f / (float)T_SEQ;
    ushort_t* outbase = ctxb + ((size_t)b * T_SEQ + q0) * DIM + (size_t)(h & 3) * 64;

    if (q0 >= sl) {   // fully masked strip: uniform softmax over all 2048 -> meanV
        #pragma unroll
        for (int nt = 0; nt < 4; ++nt) {
            ushort_t mval = f2bf(mv[h * DE + l15 + 16 * nt]);
            #pragma unroll
            for (int r = 0; r < 4; ++r)
                outbase[(size_t)(wave * 16 + quad * 4 + r) * DIM + l15 + 16 * nt] = mval;
        }
        return;
    }

    for (int i = tid; i < 384; i += 128) pdfs[i] = pdf_g[i];
    for (int i = tid; i < 288; i += 128) thrs[i] = thr_g[i];
    __syncthreads();

    short8 qa[2][2];
    #pragma unroll
    for (int g = 0; g < 2; ++g) {
        const ushort_t* qp = Qh + ((size_t)(h * T_SEQ + q0 + g * 16 + l15)) * DE + quad * 8;
        qa[g][0] = *(const short8*)(qp);
        qa[g][1] = *(const short8*)(qp + 32);
    }

    float l_acc[2][4] = {};
    floatx4 cacc[2][4];
    #pragma unroll
    for (int g = 0; g < 2; ++g)
        #pragma unroll
        for (int nt = 0; nt < 4; ++nt) cacc[g][nt] = (floatx4){0.f, 0.f, 0.f, 0.f};

    int jlo = q0 - BAND;      if (jlo < 0) jlo = 0;
    int jhi = q0 + 31 + BAND; if (jhi > sl - 1) jhi = sl - 1;   // j>=sl: all p=0
    const int jt0 = jlo >> 6, jt1e = (jhi >> 6) + 1;
    const int halfn = (jt1e - jt0 + 1) >> 1;
    const int myt0 = wave ? jt0 + halfn : jt0;
    const int myt1 = wave ? jt1e : jt0 + halfn;

    const ushort_t* Kb = Kh + (size_t)h * T_SEQ * DE;
    const ushort_t* Vb = VTp + (size_t)h * DE * T_SEQ;

    for (int jt = myt0; jt < myt1; ++jt) {
        const int j0 = jt << 6;
        const int off = j0 - q0;
        uint2 pk[2][4];
        floatx4 S[2][4];
        #pragma unroll
        for (int nt = 0; nt < 4; ++nt) {    // QK^T for all nt first (loads overlap)
            const ushort_t* kp = Kb + (size_t)(j0 + l15 + 16 * nt) * DE + quad * 8;
            short8 kb0 = *(const short8*)kp;
            short8 kb1 = *(const short8*)(kp + 32);
            floatx4 z0 = {0.f,0.f,0.f,0.f}, z1 = {0.f,0.f,0.f,0.f};
            z0 = __builtin_amdgcn_mfma_f32_16x16x32_bf16(qa[0][0], kb0, z0, 0, 0, 0);
            z0 = __builtin_amdgcn_mfma_f32_16x16x32_bf16(qa[0][1], kb1, z0, 0, 0, 0);
            z1 = __builtin_amdgcn_mfma_f32_16x16x32_bf16(qa[1][0], kb0, z1, 0, 0, 0);
            z1 = __builtin_amdgcn_mfma_f32_16x16x32_bf16(qa[1][1], kb1, z1, 0, 0, 0);
            S[0][nt] = z0; S[1][nt] = z1;
        }
        if (off >= -352 && off <= 320) {
            // FAST tile: all |delta|<=383, punish f32-normal; excl <=> j>=sl
            #pragma unroll
            for (int nt = 0; nt < 4; ++nt) {
                int jg = j0 + l15 + 16 * nt;
                bool jv = jg < sl;
                #pragma unroll
                for (int g = 0; g < 2; ++g)
                    #pragma unroll
                    for (int r = 0; r < 4; ++r) {
                        int dd = jg - (q0 + g * 16 + quad * 4 + r);
                        dd = dd < 0 ? -dd : dd;
                        float av = S[g][nt][r] * pdfs[dd];
                        av = jv ? av : -1e30f;
                        float p = __expf(av);
                        l_acc[g][r] += p;
                        unsigned hw = f2bf(p);
                        if (nt == 0)      pk[g][r].x  = hw;
                        else if (nt == 1) pk[g][r].x |= hw << 16;
                        else if (nt == 2) pk[g][r].y  = hw;
                        else              pk[g][r].y |= hw << 16;
                    }
            }
        } else {
            // BOUNDARY tile: |delta|>=321 -> exp(av)==1.0f exactly; p = incl? 1:0
            // masked j has S==0 exactly -> p=0 automatically
            #pragma unroll
            for (int nt = 0; nt < 4; ++nt) {
                int jg = j0 + l15 + 16 * nt;
                #pragma unroll
                for (int g = 0; g < 2; ++g)
                    #pragma unroll
                    for (int r = 0; r < 4; ++r) {
                        int dd = jg - (q0 + g * 16 + quad * 4 + r);
                        dd = dd < 0 ? -dd : dd;
                        float p = (fabsf(S[g][nt][r]) > thrs[dd - 321]) ? 1.0f : 0.0f;
                        l_acc[g][r] += p;
                        unsigned hw = p != 0.f ? 0x3f80u : 0u;
                        if (nt == 0)      pk[g][r].x  = hw;
                        else if (nt == 1) pk[g][r].x |= hw << 16;
                        else if (nt == 2) pk[g][r].y  = hw;
                        else              pk[g][r].y |= hw << 16;
                    }
            }
        }
        // P -> A-layout via wave-private LDS (k-permuted: col' = l15*4+nt)
        #pragma unroll
        for (int g = 0; g < 2; ++g)
            #pragma unroll
            for (int r = 0; r < 4; ++r)
                *(uint2*)&Ps[wave][g * 16 + quad * 4 + r][l15 * 4] = pk[g][r];
        short8 pa[2][2];
        #pragma unroll
        for (int g = 0; g < 2; ++g) {
            pa[g][0] = *(const short8*)&Ps[wave][g * 16 + l15][quad * 8];
            pa[g][1] = *(const short8*)&Ps[wave][g * 16 + l15][32 + quad * 8];
        }
        #pragma unroll
        for (int nt = 0; nt < 4; ++nt) {    // PV (V pre-permuted to match k order)
            const ushort_t* vp = Vb + (size_t)(l15 + 16 * nt) * T_SEQ + j0 + quad * 8;
            short8 vb0 = *(const short8*)vp;
            short8 vb1 = *(const short8*)(vp + 32);
            #pragma unroll
            for (int g = 0; g < 2; ++g) {
                floatx4 c = cacc[g][nt];
                c = __builtin_amdgcn_mfma_f32_16x16x32_bf16(pa[g][0], vb0, c, 0, 0, 0);
                c = __builtin_amdgcn_mfma_f32_16x16x32_bf16(pa[g][1], vb1, c, 0, 0, 0);
                cacc[g][nt] = c;
            }
        }
    }

    // reduce l across the 16-lane row groups
    #pragma unroll
    for (int g = 0; g < 2; ++g)
        #pragma unroll
        for (int r = 0; r < 4; ++r) {
            float lv = l_acc[g][r];
            #pragma unroll
            for (int o = 1; o <= 8; o <<= 1) lv += __shfl_xor(lv, o);
            l_acc[g][r] = lv;
        }

    if (wave == 1) {   // publish partials
        #pragma unroll
        for (int g = 0; g < 2; ++g)
            #pragma unroll
            for (int nt = 0; nt < 4; ++nt)
                #pragma unroll
                for (int r = 0; r < 4; ++r)
                    cf[g * 16 + quad * 4 + r][l15 + 16 * nt] = cacc[g][nt][r];
        if (l15 == 0)
            #pragma unroll
            for (int g = 0; g < 2; ++g)
                #pragma unroll
                for (int r = 0; r < 4; ++r)
                    lf[g * 16 + quad * 4 + r] = l_acc[g][r];
    }
    __syncthreads();
    if (wave == 0) {   // combine, normalize, store
        #pragma unroll
        for (int g = 0; g < 2; ++g)
            #pragma unroll
            for (int r = 0; r < 4; ++r) {
                int row = g * 16 + quad * 4 + r;
                int qg = q0 + row;
                float linv = 1.0f / (l_acc[g][r] + lf[row]);
                #pragma unroll
                for (int nt = 0; nt < 4; ++nt) {
                    int col = l15 + 16 * nt;
                    float o = (cacc[g][nt][r] + cf[row][col]) * linv;
                    if (qg >= sl) o = mv[h * DE + col];
                    outbase[(size_t)row * DIM + col] = f2bf(o);
                }
            }
    }
}

// ============ output projection + bias + residual (zero-LDS MFMA) ===========
__global__ __launch_bounds__(256, 2) void proj_o_mfma(
    const ushort_t* __restrict__ ctx, const ushort_t* __restrict__ wb,
    const float* __restrict__ bo, const float* __restrict__ x,
    float* __restrict__ out)
{
    const int wave = threadIdx.x >> 6, lane = threadIdx.x & 63;
    const int quad = lane >> 4, l15 = lane & 15;
    const int task = blockIdx.x * 4 + wave;      // 1024 tasks
    const int nt64 = task & 3;
    const int mstrip = task >> 2;
    const int n0 = nt64 * 64;
    const ushort_t* Wp = wb + (size_t)3 * 65536; // wo
    const int m0 = mstrip * 64;

    short8 Bf[4][8];
    #pragma unroll
    for (int nt = 0; nt < 4; ++nt) {
        int nrow = n0 + nt * 16 + l15;
        #pragma unroll
        for (int ks = 0; ks < 8; ++ks)
            Bf[nt][ks] = *(const short8*)(Wp + (size_t)nrow * 256 + ks * 32 + quad * 8);
    }
    float bias4[4];
    #pragma unroll
    for (int nt = 0; nt < 4; ++nt) bias4[nt] = bo[n0 + nt * 16 + l15];

    short8 Acur[8];
    #pragma unroll
    for (int ks = 0; ks < 8; ++ks)
        Acur[ks] = *(const short8*)(ctx + (size_t)(m0 + l15) * 256 + ks * 32 + quad * 8);

    #pragma unroll
    for (int mb = 0; mb < 4; ++mb) {
        const int mb0 = m0 + mb * 16;
        short8 Anext[8];
        if (mb < 3) {
            #pragma unroll
            for (int ks = 0; ks < 8; ++ks)
                Anext[ks] = *(const short8*)(ctx + (size_t)(mb0 + 16 + l15) * 256 + ks * 32 + quad * 8);
        }
        floatx4 acc[4];
        #pragma unroll
        for (int nt = 0; nt < 4; ++nt) acc[nt] = (floatx4){0.f, 0.f, 0.f, 0.f};
        #pragma unroll
        for (int ks = 0; ks < 8; ++ks)
            #pragma unroll
            for (int nt = 0; nt < 4; ++nt)
                acc[nt] = __builtin_amdgcn_mfma_f32_16x16x32_bf16(Acur[ks], Bf[nt][ks], acc[nt], 0, 0, 0);
        #pragma unroll
        for (int nt = 0; nt < 4; ++nt) {
            int d = n0 + nt * 16 + l15;
            #pragma unroll
            for (int r = 0; r < 4; ++r) {
                size_t mi = (size_t)(mb0 + quad * 4 + r) * 256 + d;
                out[mi] = acc[nt][r] + bias4[nt] + x[mi];
            }
        }
        #pragma unroll
        for (int ks = 0; ks < 8; ++ks) Acur[ks] = Anext[ks];
    }
}

extern "C" void kernel_launch(void* const* d_in, const int* in_sizes, int n_in,
                              void* d_out, int out_size, void* d_ws, size_t ws_size,
                              hipStream_t stream)
{
    (void)in_sizes; (void)n_in; (void)out_size; (void)ws_size;
    const float* x  = (const float*)d_in[0];
    const int*   sl = (const int*)d_in[1];
    const float* wq = (const float*)d_in[2];
    const float* bq = (const float*)d_in[3];
    const float* wk = (const float*)d_in[4];
    const float* bk = (const float*)d_in[5];
    const float* wv = (const float*)d_in[6];
    const float* bv = (const float*)d_in[7];
    const float* wo = (const float*)d_in[8];
    const float* bo = (const float*)d_in[9];
    const float* th = (const float*)d_in[10];
    float* out = (float*)d_out;

    char* ws = (char*)d_ws;
    const size_t SZH = (size_t)M_ROWS * DIM * sizeof(ushort_t);  // 8 MiB
    ushort_t* xb  = (ushort_t*)(ws);
    ushort_t* wb  = (ushort_t*)(ws + SZH);                       // 512 KiB
    ushort_t* Qh  = (ushort_t*)(ws + SZH + 524288);
    ushort_t* Kh  = (ushort_t*)(ws + 2*SZH + 524288);
    ushort_t* Vh  = (ushort_t*)(ws + 3*SZH + 524288);
    ushort_t* VTp = (ushort_t*)(ws + 4*SZH + 524288);
    ushort_t* Cb  = (ushort_t*)(ws + 5*SZH + 524288);
    float*    Mv  = (float*)   (ws + 6*SZH + 524288);            // 8 KiB
    float*    Thr = (float*)   (ws + 6*SZH + 524288 + 8192);     // 4 KiB
    float*    Pdf = (float*)   (ws + 6*SZH + 524288 + 12288);    // 4 KiB

    prep_kernel<<<dim3(2178), dim3(256), 0, stream>>>(x, wq, wk, wv, wo, th, xb, wb, Thr, Pdf);
    proj_qkv_mfma<<<dim3(768), dim3(256), 0, stream>>>(xb, wb, bq, bk, bv, sl, Qh, Kh, Vh);
    vtrans_kernel<<<dim3(NH * 8), dim3(256), 0, stream>>>(Vh, VTp);
    meanv_kernel<<<dim3(NH), dim3(256), 0, stream>>>(VTp, Mv);
    attn_mfma_kernel<<<dim3(2048), dim3(128), 0, stream>>>(Qh, Kh, VTp, Thr, Pdf, Mv, sl, Cb);
    proj_o_mfma<<<dim3(256), dim3(256), 0, stream>>>(Cb, wb, bo, x, out);
}

// Round 7
// 186.570 us; speedup vs baseline: 1.1544x; 1.1544x over previous
//
#include <hip/hip_runtime.h>
#include <math.h>
#include <stdint.h>

#define B_SZ   8
#define T_SEQ  2048
#define DIM    256
#define NH     32            // B*E
#define DE     64
#define BAND   509           // |j-i|<=509 can have nonzero f32 punish (denormals)
#define M_ROWS (B_SZ * T_SEQ)

typedef __attribute__((ext_vector_type(8))) short short8;   // 8 bf16 (4 VGPRs)
typedef __attribute__((ext_vector_type(4))) float floatx4;  // MFMA C/D frag
typedef unsigned short ushort_t;

__device__ __forceinline__ ushort_t f2bf(float x) {   // RNE f32->bf16
    unsigned u = __float_as_uint(x);
    u += 0x7fffu + ((u >> 16) & 1u);
    return (ushort_t)(u >> 16);
}
__device__ __forceinline__ float bf2f(ushort_t b) {
    return __uint_as_float(((unsigned)b) << 16);
}
__device__ __forceinline__ unsigned pack2(float a, float b) {
    return (unsigned)f2bf(a) | ((unsigned)f2bf(b) << 16);
}

__device__ __forceinline__ double pd_exact(int d, float th) {
    float df  = (float)d;
    float arg = (-(df * df)) / (th * th);      // exact same f32 ops as numpy
    double pdd = exp((double)arg);
    if (pdd < 1.17549435082228751e-38)
        return rint(pdd * 0x1p149) * 0x1p-149; // f32 RNE into denormal range
    return (double)(float)pdd;
}

// ============ prep: x,w -> bf16; pdf[0..383] + thr[|d|-321, 0..287] =========
__global__ __launch_bounds__(256) void prep_kernel(
    const float* __restrict__ x,
    const float* __restrict__ wq, const float* __restrict__ wk,
    const float* __restrict__ wv, const float* __restrict__ wo,
    const float* __restrict__ theta,
    ushort_t* __restrict__ xb, ushort_t* __restrict__ wb,
    float* __restrict__ thr_g, float* __restrict__ pdf_g)
{
    const int bid = blockIdx.x, tid = threadIdx.x;
    if (bid < 2048) {
        size_t i8 = ((size_t)bid * 256 + tid) * 8;
        float4 a = *(const float4*)(x + i8);
        float4 b = *(const float4*)(x + i8 + 4);
        uint4 o;
        o.x = pack2(a.x, a.y); o.y = pack2(a.z, a.w);
        o.z = pack2(b.x, b.y); o.w = pack2(b.z, b.w);
        *(uint4*)(xb + i8) = o;
    } else if (bid < 2176) {
        size_t w8 = ((size_t)(bid - 2048) * 256 + tid) * 8;
        int which = (int)(w8 >> 16);
        const float* src = (which == 0) ? wq : (which == 1) ? wk : (which == 2) ? wv : wo;
        size_t off = w8 & 65535;
        float4 a = *(const float4*)(src + off);
        float4 b = *(const float4*)(src + off + 4);
        uint4 o;
        o.x = pack2(a.x, a.y); o.y = pack2(a.z, a.w);
        o.z = pack2(b.x, b.y); o.w = pack2(b.z, b.w);
        *(uint4*)(wb + w8) = o;
    } else {
        int i = (bid - 2176) * 256 + tid;
        float th = theta[0];
        if (i < 384) pdf_g[i] = (float)pd_exact(i, th);
        if (i < 288) {
            double pdv = pd_exact(321 + i, th);
            // exclusion: RN32(s*pd)==0  <=>  |s| <= 2^-150/pd
            thr_g[i] = (pdv == 0.0) ? __builtin_inff() : (float)(0x1p-150 / pdv);
        }
    }
}

// ============ QKV projection: MFMA GEMM + transposed coalesced epilogue =====
// head map: h=b*4+d/64, q=(d%64)*32+t/64, e=t%64.  Qh/Kh masked q>=sl -> 0.
__global__ __launch_bounds__(256, 2) void proj_qkv_mfma(
    const ushort_t* __restrict__ xb, const ushort_t* __restrict__ wb,
    const float* __restrict__ bq, const float* __restrict__ bk,
    const float* __restrict__ bv, const int* __restrict__ seq_len,
    ushort_t* __restrict__ Qh, ushort_t* __restrict__ Kh, ushort_t* __restrict__ Vh)
{
    __shared__ __align__(16) ushort_t Ls[4][64][68];   // per-wave [d][t] slab
    const int wave = threadIdx.x >> 6, lane = threadIdx.x & 63;
    const int quad = lane >> 4, l15 = lane & 15;
    const int task = blockIdx.x * 4 + wave;      // 3072 tasks
    const int nt64 = task % 12;
    const int mstrip = task / 12;
    const int mode = nt64 >> 2;                  // 0:Q 1:K 2:V
    const int nloc_base = (nt64 & 3) * 64;       // d within [0,256)
    const ushort_t* Wp = wb + (size_t)mode * 65536;
    const int m0 = mstrip * 64;
    const int bb = m0 >> 11;
    const int th0 = (m0 >> 6) & 31;
    const int sl = seq_len[bb];
    ushort_t* outp = (mode == 0) ? Qh : (mode == 1) ? Kh : Vh;
    const float* bias = (mode == 0) ? bq : (mode == 1) ? bk : bv;
    const int hh = bb * 4 + (nloc_base >> 6);
    const float oscale = (mode == 0) ? 0.022097086912079612f : 1.0f;  // 1/sqrt(2048)

    short8 Bf[4][8];
    #pragma unroll
    for (int nt = 0; nt < 4; ++nt) {
        int nrow = nloc_base + nt * 16 + l15;
        #pragma unroll
        for (int ks = 0; ks < 8; ++ks)
            Bf[nt][ks] = *(const short8*)(Wp + (size_t)nrow * 256 + ks * 32 + quad * 8);
    }
    float bias4[4];
    #pragma unroll
    for (int nt = 0; nt < 4; ++nt) bias4[nt] = bias[nloc_base + nt * 16 + l15];

    short8 Acur[8];
    #pragma unroll
    for (int ks = 0; ks < 8; ++ks)
        Acur[ks] = *(const short8*)(xb + (size_t)(m0 + l15) * 256 + ks * 32 + quad * 8);

    #pragma unroll
    for (int mb = 0; mb < 4; ++mb) {
        const int mb0 = m0 + mb * 16;
        short8 Anext[8];
        if (mb < 3) {
            #pragma unroll
            for (int ks = 0; ks < 8; ++ks)
                Anext[ks] = *(const short8*)(xb + (size_t)(mb0 + 16 + l15) * 256 + ks * 32 + quad * 8);
        }
        floatx4 acc[4];
        #pragma unroll
        for (int nt = 0; nt < 4; ++nt) acc[nt] = (floatx4){0.f, 0.f, 0.f, 0.f};
        #pragma unroll
        for (int ks = 0; ks < 8; ++ks)
            #pragma unroll
            for (int nt = 0; nt < 4; ++nt)
                acc[nt] = __builtin_amdgcn_mfma_f32_16x16x32_bf16(Acur[ks], Bf[nt][ks], acc[nt], 0, 0, 0);
        // stash into wave-private slab, [d][t] layout, packed b64
        #pragma unroll
        for (int nt = 0; nt < 4; ++nt) {
            float v0 = (acc[nt][0] + bias4[nt]) * oscale;
            float v1 = (acc[nt][1] + bias4[nt]) * oscale;
            float v2 = (acc[nt][2] + bias4[nt]) * oscale;
            float v3 = (acc[nt][3] + bias4[nt]) * oscale;
            uint2 pk; pk.x = pack2(v0, v1); pk.y = pack2(v2, v3);
            *(uint2*)&Ls[wave][nt * 16 + l15][mb * 16 + quad * 4] = pk;
        }
        #pragma unroll
        for (int ks = 0; ks < 8; ++ks) Acur[ks] = Anext[ks];
    }

    // coalesced store: row q = dl*32+th0, 128B of e contiguous
    #pragma unroll
    for (int s = 0; s < 16; ++s) {
        int dl = s * 4 + quad;
        int e0 = l15 * 4;
        uint2 pk = *(const uint2*)&Ls[wave][dl][e0];
        int q = dl * 32 + th0;
        if (mode <= 1 && q >= sl) { pk.x = 0u; pk.y = 0u; }
        *(uint2*)(outp + (((size_t)hh * T_SEQ + q) << 6) + e0) = pk;
    }
}

// ============ V transpose with MFMA-k permutation: VTp[h][e][j'] ============
// phys col c (within each 64-j block) holds j = (c>>2) + 16*(c&3), matching
// attn's b64 Ps writes (col' = l15*4+nt) and V B-frag phys-k order
__global__ __launch_bounds__(256) void vtrans_kernel(const ushort_t* __restrict__ Vh,
                                                     ushort_t* __restrict__ VTp)
{
    __shared__ ushort_t Vs[256][66];
    const int tid = threadIdx.x;
    const int h = blockIdx.x >> 3, chunk = blockIdx.x & 7;
    const ushort_t* src = Vh + ((size_t)(h * T_SEQ + chunk * 256)) * DE;
    #pragma unroll
    for (int rep = 0; rep < 8; ++rep) {
        int f = rep * 256 + tid;
        int row = f >> 3, c8 = (f & 7) * 8;
        *(uint4*)&Vs[row][c8] = *(const uint4*)(src + (size_t)row * DE + c8);
    }
    __syncthreads();
    const int w = tid >> 6, lane = tid & 63;
    const int half = lane >> 5;
    const int c32 = lane & 31;
    const int cbase = c32 * 8;
    const int blk = cbase >> 6;
    const int cin = cbase & 63;
    #pragma unroll
    for (int rr = 0; rr < 8; ++rr) {
        int e = w * 16 + rr * 2 + half;
        ushort_t tmp[8];
        #pragma unroll
        for (int t = 0; t < 8; ++t) {
            int ci = cin + t;
            int j = blk * 64 + (ci >> 2) + 16 * (ci & 3);
            tmp[t] = Vs[j][e];
        }
        *(uint4*)(VTp + ((size_t)(h * DE + e)) * T_SEQ + chunk * 256 + cbase) = *(uint4*)tmp;
    }
}

// ============ per-head SUM of V (coalesced, 8 blocks/head, atomic) ==========
// Mv zeroed before launch; holds column sums (multiply by 1/T at use site)
__global__ __launch_bounds__(256) void meanv_partial(const ushort_t* __restrict__ Vh,
                                                     float* __restrict__ mv) {
    __shared__ float red[32][72];
    const int blk = blockIdx.x;          // 256 = 32 heads x 8 chunks
    const int h = blk >> 3, chunk = blk & 7;
    const int tid = threadIdx.x;
    const int r0 = tid >> 3;             // 0..31
    const int es = (tid & 7) * 8;        // e-slice
    const ushort_t* p = Vh + ((size_t)h * T_SEQ + chunk * 256 + r0) * DE + es;
    float s[8] = {};
    #pragma unroll
    for (int k = 0; k < 8; ++k) {        // rows r0 + 32*k
        uint4 u = *(const uint4*)(p + (size_t)k * 32 * DE);
        const ushort_t* w = (const ushort_t*)&u;
        #pragma unroll
        for (int i = 0; i < 8; ++i) s[i] += bf2f(w[i]);
    }
    #pragma unroll
    for (int i = 0; i < 8; ++i) red[r0][es + i] = s[i];
    __syncthreads();
    if (tid < 64) {
        float t = 0.f;
        #pragma unroll
        for (int g = 0; g < 32; ++g) t += red[g][tid];
        atomicAdd(&mv[h * DE + tid], t);
    }
}

// ============ banded flash attention: R5 shape + VTp staging + b64 Ps =======
__global__ __launch_bounds__(256) void attn_mfma_kernel(
    const ushort_t* __restrict__ Qh, const ushort_t* __restrict__ Kh,
    const ushort_t* __restrict__ VTp, const float* __restrict__ thr_g,
    const float* __restrict__ pdf_g, const float* __restrict__ mvs,
    const int* __restrict__ seq_len, ushort_t* __restrict__ ctxb)
{
    __shared__ ushort_t Ks [64][72];   // [j][e]
    __shared__ ushort_t VTs[64][72];   // [e][j'-perm] staged from VTp
    __shared__ ushort_t Ps [4][16][72];
    __shared__ float pdfs[384];        // punish, |delta| 0..383
    __shared__ float thrs[288];        // thr, |delta|-321 (321..608)

    const int tid  = threadIdx.x;
    const int wave = tid >> 6;
    const int lane = tid & 63;
    const int quad = lane >> 4;
    const int l15  = lane & 15;
    // XCD swizzle: 4 heads per XCD, all q-strips of a head on one XCD
    const int bid   = blockIdx.x;
    const int inner = bid >> 3;
    const int h  = ((inner >> 5) << 3) | (bid & 7);
    const int q0 = (inner & 31) * 64;
    const int b  = h >> 2;
    const int sl = seq_len[b];
    const float invT = 1.0f / (float)T_SEQ;
    ushort_t* outbase = ctxb + ((size_t)b * T_SEQ + q0) * DIM + (size_t)(h & 3) * 64;

    if (q0 >= sl) {   // fully masked strip: uniform softmax over all 2048 -> meanV
        #pragma unroll
        for (int nt = 0; nt < 4; ++nt) {
            ushort_t mval = f2bf(mvs[h * DE + l15 + 16 * nt] * invT);
            #pragma unroll
            for (int r = 0; r < 4; ++r)
                outbase[(size_t)(wave * 16 + quad * 4 + r) * DIM + l15 + 16 * nt] = mval;
        }
        return;
    }

    for (int i = tid; i < 384; i += 256) pdfs[i] = pdf_g[i];
    for (int i = tid; i < 288; i += 256) thrs[i] = thr_g[i];

    short8 qa0, qa1;
    {
        const ushort_t* qp = Qh + ((size_t)h * T_SEQ + q0 + wave * 16 + l15) * DE + quad * 8;
        qa0 = *(const short8*)(qp);
        qa1 = *(const short8*)(qp + 32);
    }

    float l_acc[4] = {0.f, 0.f, 0.f, 0.f};
    floatx4 cacc[4];
    #pragma unroll
    for (int nt = 0; nt < 4; ++nt) cacc[nt] = (floatx4){0.f, 0.f, 0.f, 0.f};

    int jlo = q0 - BAND;      if (jlo < 0) jlo = 0;
    int jhi = q0 + 63 + BAND; if (jhi > sl - 1) jhi = sl - 1;   // j>=sl: all p=0
    const int jt0 = jlo >> 6, jt1 = jhi >> 6;

    // register prefetch of K/V tiles (hides global latency behind compute)
    const int krow = tid >> 3;           // 0..31
    const int kc8  = (tid & 7) * 8;
    const ushort_t* Kbp = Kh + (size_t)h * T_SEQ * DE;
    const ushort_t* Vbp = VTp + (size_t)h * DE * T_SEQ;
    uint4 kpre0, kpre1, vpre0, vpre1;
    {
        const int j0 = jt0 << 6;
        kpre0 = *(const uint4*)(Kbp + (size_t)(j0 + krow) * DE + kc8);
        kpre1 = *(const uint4*)(Kbp + (size_t)(j0 + krow + 32) * DE + kc8);
        vpre0 = *(const uint4*)(Vbp + (size_t)krow * T_SEQ + j0 + kc8);
        vpre1 = *(const uint4*)(Vbp + (size_t)(krow + 32) * T_SEQ + j0 + kc8);
    }

    for (int jt = jt0; jt <= jt1; ++jt) {
        const int j0 = jt << 6;
        __syncthreads();
        *(uint4*)&Ks[krow][kc8]       = kpre0;
        *(uint4*)&Ks[krow + 32][kc8]  = kpre1;
        *(uint4*)&VTs[krow][kc8]      = vpre0;
        *(uint4*)&VTs[krow + 32][kc8] = vpre1;
        __syncthreads();
        if (jt < jt1) {   // next tile's loads fly during compute
            const int jn = j0 + 64;
            kpre0 = *(const uint4*)(Kbp + (size_t)(jn + krow) * DE + kc8);
            kpre1 = *(const uint4*)(Kbp + (size_t)(jn + krow + 32) * DE + kc8);
            vpre0 = *(const uint4*)(Vbp + (size_t)krow * T_SEQ + jn + kc8);
            vpre1 = *(const uint4*)(Vbp + (size_t)(krow + 32) * T_SEQ + jn + kc8);
        }

        // S = Q K^T (already scaled by 1/sqrt(T) via Q)
        floatx4 S[4];
        #pragma unroll
        for (int nt = 0; nt < 4; ++nt) {
            short8 kb0 = *(const short8*)&Ks[l15 + 16 * nt][quad * 8];
            short8 kb1 = *(const short8*)&Ks[l15 + 16 * nt][32 + quad * 8];
            floatx4 z = {0.f, 0.f, 0.f, 0.f};
            z = __builtin_amdgcn_mfma_f32_16x16x32_bf16(qa0, kb0, z, 0, 0, 0);
            z = __builtin_amdgcn_mfma_f32_16x16x32_bf16(qa1, kb1, z, 0, 0, 0);
            S[nt] = z;
        }

        // weights p = exp(s*punish) (no max-subtract; softmax shift-invariant)
        const int off = j0 - q0;
        float p[4][4];
        if (off >= -320 && off <= 320) {
            // FAST: |delta|<=383 -> punish from LDS table; excl <=> j>=sl
            #pragma unroll
            for (int nt = 0; nt < 4; ++nt) {
                int jg = j0 + l15 + 16 * nt;
                bool jv = (jg < sl);
                #pragma unroll
                for (int r = 0; r < 4; ++r) {
                    int dd = jg - (q0 + wave * 16 + quad * 4 + r);
                    dd = dd < 0 ? -dd : dd;
                    float av = S[nt][r] * pdfs[dd];
                    av = jv ? av : -1e30f;
                    p[nt][r] = __expf(av);
                }
            }
        } else {
            // BOUNDARY: |delta|>=321 -> exp(av)==1.0f exactly; p = incl? 1:0
            // masked j has S==0 exactly -> p=0 automatically
            #pragma unroll
            for (int nt = 0; nt < 4; ++nt) {
                int jg = j0 + l15 + 16 * nt;
                #pragma unroll
                for (int r = 0; r < 4; ++r) {
                    int dd = jg - (q0 + wave * 16 + quad * 4 + r);
                    dd = dd < 0 ? -dd : dd;
                    p[nt][r] = (fabsf(S[nt][r]) > thrs[dd - 321]) ? 1.0f : 0.0f;
                }
            }
        }

        // P -> A-layout via wave-private LDS, k-permuted b64 writes
        #pragma unroll
        for (int r = 0; r < 4; ++r) {
            l_acc[r] += (p[0][r] + p[1][r]) + (p[2][r] + p[3][r]);
            uint2 pk;
            pk.x = pack2(p[0][r], p[1][r]);
            pk.y = pack2(p[2][r], p[3][r]);
            *(uint2*)&Ps[wave][quad * 4 + r][l15 * 4] = pk;
        }
        short8 pa0 = *(const short8*)&Ps[wave][l15][quad * 8];
        short8 pa1 = *(const short8*)&Ps[wave][l15][32 + quad * 8];
        #pragma unroll
        for (int nt = 0; nt < 4; ++nt) {   // PV (VTs phys-k order matches Ps)
            short8 vb0 = *(const short8*)&VTs[l15 + 16 * nt][quad * 8];
            short8 vb1 = *(const short8*)&VTs[l15 + 16 * nt][32 + quad * 8];
            floatx4 c = cacc[nt];
            c = __builtin_amdgcn_mfma_f32_16x16x32_bf16(pa0, vb0, c, 0, 0, 0);
            c = __builtin_amdgcn_mfma_f32_16x16x32_bf16(pa1, vb1, c, 0, 0, 0);
            cacc[nt] = c;
        }
    }

    // final: reduce l across the 16-lane row group, divide, store
    #pragma unroll
    for (int r = 0; r < 4; ++r) {
        float lv = l_acc[r];
        #pragma unroll
        for (int o = 1; o <= 8; o <<= 1) lv += __shfl_xor(lv, o);
        l_acc[r] = 1.0f / lv;
    }
    #pragma unroll
    for (int nt = 0; nt < 4; ++nt) {
        #pragma unroll
        for (int r = 0; r < 4; ++r) {
            int row = wave * 16 + quad * 4 + r;
            int qg = q0 + row;
            float o = cacc[nt][r] * l_acc[r];
            if (qg >= sl) o = mvs[h * DE + l15 + 16 * nt] * invT;
            outbase[(size_t)row * DIM + l15 + 16 * nt] = f2bf(o);
        }
    }
}

// ============ output projection + bias + residual (zero-LDS MFMA) ===========
__global__ __launch_bounds__(256, 2) void proj_o_mfma(
    const ushort_t* __restrict__ ctx, const ushort_t* __restrict__ wb,
    const float* __restrict__ bo, const float* __restrict__ x,
    float* __restrict__ out)
{
    const int wave = threadIdx.x >> 6, lane = threadIdx.x & 63;
    const int quad = lane >> 4, l15 = lane & 15;
    const int task = blockIdx.x * 4 + wave;      // 1024 tasks
    const int nt64 = task & 3;
    const int mstrip = task >> 2;
    const int n0 = nt64 * 64;
    const ushort_t* Wp = wb + (size_t)3 * 65536; // wo
    const int m0 = mstrip * 64;

    short8 Bf[4][8];
    #pragma unroll
    for (int nt = 0; nt < 4; ++nt) {
        int nrow = n0 + nt * 16 + l15;
        #pragma unroll
        for (int ks = 0; ks < 8; ++ks)
            Bf[nt][ks] = *(const short8*)(Wp + (size_t)nrow * 256 + ks * 32 + quad * 8);
    }
    float bias4[4];
    #pragma unroll
    for (int nt = 0; nt < 4; ++nt) bias4[nt] = bo[n0 + nt * 16 + l15];

    short8 Acur[8];
    #pragma unroll
    for (int ks = 0; ks < 8; ++ks)
        Acur[ks] = *(const short8*)(ctx + (size_t)(m0 + l15) * 256 + ks * 32 + quad * 8);

    #pragma unroll
    for (int mb = 0; mb < 4; ++mb) {
        const int mb0 = m0 + mb * 16;
        short8 Anext[8];
        if (mb < 3) {
            #pragma unroll
            for (int ks = 0; ks < 8; ++ks)
                Anext[ks] = *(const short8*)(ctx + (size_t)(mb0 + 16 + l15) * 256 + ks * 32 + quad * 8);
        }
        floatx4 acc[4];
        #pragma unroll
        for (int nt = 0; nt < 4; ++nt) acc[nt] = (floatx4){0.f, 0.f, 0.f, 0.f};
        #pragma unroll
        for (int ks = 0; ks < 8; ++ks)
            #pragma unroll
            for (int nt = 0; nt < 4; ++nt)
                acc[nt] = __builtin_amdgcn_mfma_f32_16x16x32_bf16(Acur[ks], Bf[nt][ks], acc[nt], 0, 0, 0);
        #pragma unroll
        for (int nt = 0; nt < 4; ++nt) {
            int d = n0 + nt * 16 + l15;
            #pragma unroll
            for (int r = 0; r < 4; ++r) {
                size_t mi = (size_t)(mb0 + quad * 4 + r) * 256 + d;
                out[mi] = acc[nt][r] + bias4[nt] + x[mi];
            }
        }
        #pragma unroll
        for (int ks = 0; ks < 8; ++ks) Acur[ks] = Anext[ks];
    }
}

extern "C" void kernel_launch(void* const* d_in, const int* in_sizes, int n_in,
                              void* d_out, int out_size, void* d_ws, size_t ws_size,
                              hipStream_t stream)
{
    (void)in_sizes; (void)n_in; (void)out_size; (void)ws_size;
    const float* x  = (const float*)d_in[0];
    const int*   sl = (const int*)d_in[1];
    const float* wq = (const float*)d_in[2];
    const float* bq = (const float*)d_in[3];
    const float* wk = (const float*)d_in[4];
    const float* bk = (const float*)d_in[5];
    const float* wv = (const float*)d_in[6];
    const float* bv = (const float*)d_in[7];
    const float* wo = (const float*)d_in[8];
    const float* bo = (const float*)d_in[9];
    const float* th = (const float*)d_in[10];
    float* out = (float*)d_out;

    char* ws = (char*)d_ws;
    const size_t SZH = (size_t)M_ROWS * DIM * sizeof(ushort_t);  // 8 MiB
    ushort_t* xb  = (ushort_t*)(ws);
    ushort_t* wb  = (ushort_t*)(ws + SZH);                       // 512 KiB
    ushort_t* Qh  = (ushort_t*)(ws + SZH + 524288);
    ushort_t* Kh  = (ushort_t*)(ws + 2*SZH + 524288);
    ushort_t* Vh  = (ushort_t*)(ws + 3*SZH + 524288);
    ushort_t* VTp = (ushort_t*)(ws + 4*SZH + 524288);
    ushort_t* Cb  = (ushort_t*)(ws + 5*SZH + 524288);
    float*    Mv  = (float*)   (ws + 6*SZH + 524288);            // 8 KiB
    float*    Thr = (float*)   (ws + 6*SZH + 524288 + 8192);     // 4 KiB
    float*    Pdf = (float*)   (ws + 6*SZH + 524288 + 12288);    // 4 KiB

    hipMemsetAsync(Mv, 0, NH * DE * sizeof(float), stream);
    prep_kernel<<<dim3(2178), dim3(256), 0, stream>>>(x, wq, wk, wv, wo, th, xb, wb, Thr, Pdf);
    proj_qkv_mfma<<<dim3(768), dim3(256), 0, stream>>>(xb, wb, bq, bk, bv, sl, Qh, Kh, Vh);
    vtrans_kernel<<<dim3(NH * 8), dim3(256), 0, stream>>>(Vh, VTp);
    meanv_partial<<<dim3(256), dim3(256), 0, stream>>>(Vh, Mv);
    attn_mfma_kernel<<<dim3(1024), dim3(256), 0, stream>>>(Qh, Kh, VTp, Thr, Pdf, Mv, sl, Cb);
    proj_o_mfma<<<dim3(256), dim3(256), 0, stream>>>(Cb, wb, bo, x, out);
}